// Round 5
// baseline (819.599 us; speedup 1.0000x reference)
//
#include <hip/hip_runtime.h>
#include <cmath>

#define BSZ 8
#define TT  1024
#define EE  512
#define HH  8
#define CUc 6
#define HDD 64

typedef __bf16 bf16;
typedef __attribute__((ext_vector_type(4))) float f32x4;
typedef __attribute__((ext_vector_type(8))) float f32x8;
typedef __attribute__((ext_vector_type(8))) bf16  bf16x8;

static __device__ __forceinline__ f32x4 mfma16(bf16x8 a, bf16x8 b, f32x4 c) {
    return __builtin_amdgcn_mfma_f32_16x16x32_bf16(a, b, c, 0, 0, 0);
}

// ---------------------------------------------------------------- k_split_all
__global__ __launch_bounds__(256) void k_split_all(
    const float* __restrict__ wq, const float* __restrict__ wk,
    const float* __restrict__ wv, const float* __restrict__ wo,
    const float* __restrict__ x,
    bf16* __restrict__ wqh, bf16* __restrict__ wql,
    bf16* __restrict__ wkh, bf16* __restrict__ wkl,
    bf16* __restrict__ wvh, bf16* __restrict__ woh,
    bf16* __restrict__ xh,  bf16* __restrict__ xl)
{
    const float* src; bf16* hi; bf16* lo; int n;
    switch (blockIdx.y) {
        case 0: src = wq; hi = wqh; lo = wql;     n = EE * EE;       break;
        case 1: src = wk; hi = wkh; lo = wkl;     n = EE * EE;       break;
        case 2: src = wv; hi = wvh; lo = nullptr; n = EE * EE;       break;
        case 3: src = wo; hi = woh; lo = nullptr; n = EE * EE;       break;
        default: src = x; hi = xh;  lo = xl;      n = BSZ * TT * EE; break;
    }
    const int i = (blockIdx.x * 256 + threadIdx.x) * 8;
    if (i >= n) return;
    f32x8 v = *(const f32x8*)(src + i);
    bf16x8 h8, l8;
#pragma unroll
    for (int k = 0; k < 8; ++k) {
        bf16 h = (bf16)v[k];
        h8[k] = h;
        l8[k] = (bf16)(v[k] - (float)h);
    }
    *(bf16x8*)(hi + i) = h8;
    if (lo) *(bf16x8*)(lo + i) = l8;
}

// ---------------------------------------------------------------- k_proj2 (unchanged)
__global__ __launch_bounds__(256) void k_proj2(
    const bf16* __restrict__ xh, const bf16* __restrict__ xl,
    const bf16* __restrict__ wqh, const bf16* __restrict__ wql,
    const bf16* __restrict__ wkh, const bf16* __restrict__ wkl,
    const bf16* __restrict__ wvh,
    bf16* __restrict__ Qh, bf16* __restrict__ Ql,
    bf16* __restrict__ Kh, bf16* __restrict__ Kl,
    bf16* __restrict__ Vt)
{
    const int rb = blockIdx.x;
    const int cb = blockIdx.y;
    const int wid = threadIdx.x >> 6;
    const int l   = threadIdx.x & 63;
    const int lg = l >> 4, lr = l & 15;
    const int row = rb * 64 + wid * 16 + lr;

    f32x4 aq[4], ak[4], av[4];
#pragma unroll
    for (int c = 0; c < 4; ++c) {
        aq[c] = f32x4{0.f,0.f,0.f,0.f}; ak[c] = f32x4{0.f,0.f,0.f,0.f}; av[c] = f32x4{0.f,0.f,0.f,0.f};
    }

    for (int ks = 0; ks < 16; ++ks) {
        const int e0 = ks * 32 + lg * 8;
        bf16x8 xhv = *(const bf16x8*)(xh + (size_t)row * EE + e0);
        bf16x8 xlv = *(const bf16x8*)(xl + (size_t)row * EE + e0);
#pragma unroll
        for (int c = 0; c < 4; ++c) {
            const int f = cb * 64 + c * 16 + lr;
            const size_t wo = (size_t)f * EE + e0;
            bf16x8 qh = *(const bf16x8*)(wqh + wo);
            bf16x8 ql = *(const bf16x8*)(wql + wo);
            bf16x8 kh = *(const bf16x8*)(wkh + wo);
            bf16x8 kl = *(const bf16x8*)(wkl + wo);
            bf16x8 vh = *(const bf16x8*)(wvh + wo);
            aq[c] = mfma16(xhv, qh, aq[c]); aq[c] = mfma16(xhv, ql, aq[c]); aq[c] = mfma16(xlv, qh, aq[c]);
            ak[c] = mfma16(xhv, kh, ak[c]); ak[c] = mfma16(xhv, kl, ak[c]); ak[c] = mfma16(xlv, kh, ak[c]);
            av[c] = mfma16(xhv, vh, av[c]);
        }
    }

#pragma unroll
    for (int c = 0; c < 4; ++c)
#pragma unroll
        for (int r = 0; r < 4; ++r) {
            const int orow = rb * 64 + wid * 16 + lg * 4 + r;
            const int b = orow >> 10, t = orow & 1023;
            const int f = cb * 64 + c * 16 + lr;
            const int h = f >> 6, d = f & 63;
            const size_t idx = ((size_t)(b * HH + h) * TT + t) * HDD + d;
            float vq = aq[c][r];
            bf16 qhi = (bf16)vq; Qh[idx] = qhi; Ql[idx] = (bf16)(vq - (float)qhi);
            float vk = ak[c][r];
            bf16 khi = (bf16)vk; Kh[idx] = khi; Kl[idx] = (bf16)(vk - (float)khi);
            Vt[(((size_t)(b * HH + h) * HDD + d) * TT) + t] = (bf16)av[c][r];
        }
}

// ---------------------------------------------------------------- k_ubias2 (R2 layout: coalesced writes)
// UB chunk (b,h,i16) = (bf16*)(A + ((bh*1024 + i16*16) * 1024)); layout [i&15][j]
__global__ __launch_bounds__(256) void k_ubias2(
    const float* __restrict__ u, const unsigned char* __restrict__ umask,
    const float* __restrict__ wu, const float* __restrict__ bu,
    float* __restrict__ A)
{
    __shared__ __align__(16) unsigned char msk[64][64];   // [j-rel][i-rel]
    const int b  = blockIdx.z;
    const int i0 = blockIdx.y * 64;
    const int j0 = blockIdx.x * 64;
    const int t  = threadIdx.x;

    {
        const int jj  = t >> 2;
        const int seg = (t & 3) * 16;
        *(uint4*)(&msk[jj][seg]) =
            *(const uint4*)(umask + ((size_t)b * TT + (j0 + jj)) * TT + i0 + seg);
    }
    float wuv[HH][CUc], buv[HH];
#pragma unroll
    for (int h = 0; h < HH; ++h) {
        buv[h] = bu[h];
#pragma unroll
        for (int c = 0; c < CUc; ++c) wuv[h][c] = wu[h * CUc + c];
    }
    __syncthreads();

    const int j = j0 + (t & 63);
    for (int ii = (t >> 6); ii < 64; ii += 4) {
        const int i = i0 + ii;
        float uv[CUc];
#pragma unroll
        for (int c = 0; c < CUc; ++c)
            uv[c] = u[(((size_t)b * CUc + c) * TT + i) * TT + j];
        const bool mk = msk[t & 63][ii] != 0;
#pragma unroll
        for (int h = 0; h < HH; ++h) {
            float v = buv[h];
#pragma unroll
            for (int c = 0; c < CUc; ++c) v += uv[c] * wuv[h][c];
            if (mk) v = -INFINITY;
            bf16* ub = (bf16*)(A + ((size_t)(b * HH + h) * TT + (i & ~15)) * TT);
            ub[(i & 15) * TT + j] = (bf16)v;
        }
    }
}

// ---------------------------------------------------------------- k_fused4: flash attention
// Block = (b,h,128 q-rows); 8 waves x 16 q-rows each, full j per wave (no cross-wave coupling).
// K/V staged in XOR-swizzled LDS per 128-j tile. Online softmax; ctx in regs.
// Writes p (bf16, vs running max) to 2nd half of A row-span + m_tile/S sidecars.
#define MTOFF  ((size_t)64 * 1024 * 8)    // f32 elems: m_tile region size; S follows
__global__ __launch_bounds__(512, 4) void k_fused4(
    const bf16* __restrict__ Qh, const bf16* __restrict__ Ql,
    const bf16* __restrict__ Kh, const bf16* __restrict__ Kl,
    const bf16* __restrict__ Vt,
    float* __restrict__ A, bf16* __restrict__ ctx, float* __restrict__ mS)
{
    const int blk = blockIdx.x;
    const int bh  = blk & 63;               // same (b,h) -> same XCD (blk%8)
    const int b   = bh >> 3, h = bh & 7;
    const int i0  = (blk >> 6) * 128;
    const int w   = threadIdx.x >> 6;
    const int l   = threadIdx.x & 63;
    const int lg  = l >> 4, lr = l & 15;
    const int iw  = i0 + w * 16;            // this wave's 16 q-rows

    __shared__ __align__(16) bf16 Ksh[2][128 * 64];   // 32 KB (hi,lo), swizzled
    __shared__ __align__(16) bf16 Vsh[64 * 128];      // 16 KB, swizzled
    __shared__ __align__(16) bf16 Psh[8][16 * 128];   // 32 KB (4KB per wave), swizzled

    // Q fragments (once)
    const bf16* qph = Qh + ((size_t)bh * TT + iw) * HDD;
    const bf16* qpl = Ql + ((size_t)bh * TT + iw) * HDD;
    bf16x8 qh0 = *(const bf16x8*)(qph + lr * HDD + lg * 8);
    bf16x8 qh1 = *(const bf16x8*)(qph + lr * HDD + 32 + lg * 8);
    bf16x8 ql0 = *(const bf16x8*)(qpl + lr * HDD + lg * 8);
    bf16x8 ql1 = *(const bf16x8*)(qpl + lr * HDD + 32 + lg * 8);

    const bf16* ubc = (const bf16*)(A + ((size_t)bh * TT + iw) * TT);        // UB (1st half)
    bf16*       pA  = (bf16*)(A + ((size_t)bh * TT + iw) * TT) + 16 * TT;    // p  (2nd half)

    float mrun[4], srun[4];
    f32x4 cacc[4];
#pragma unroll
    for (int r = 0; r < 4; ++r) { mrun[r] = -INFINITY; srun[r] = 0.f; }
#pragma unroll
    for (int dt = 0; dt < 4; ++dt) cacc[dt] = f32x4{0.f,0.f,0.f,0.f};

    for (int tile = 0; tile < 8; ++tile) {
        const int j0 = tile * 128;
        __syncthreads();                               // LDS free of prior readers
        {   // ---- cooperative stage: Kh,Kl (128 rows x 64), V (64 d x 128 t), XOR-swizzled
            const int tid = threadIdx.x;
            const int kr  = tid >> 2;                  // 0..127
            const int ks0 = (tid & 3) * 2;             // seg pairs (8 bf16 per seg)
            const bf16* gkh = Kh + ((size_t)bh * TT + j0 + kr) * HDD;
            const bf16* gkl = Kl + ((size_t)bh * TT + j0 + kr) * HDD;
            const int sw0 = (ks0     ^ (kr & 7));
            const int sw1 = ((ks0+1) ^ (kr & 7));
            *(bf16x8*)&Ksh[0][kr * 64 + sw0 * 8] = *(const bf16x8*)(gkh + ks0 * 8);
            *(bf16x8*)&Ksh[0][kr * 64 + sw1 * 8] = *(const bf16x8*)(gkh + (ks0+1) * 8);
            *(bf16x8*)&Ksh[1][kr * 64 + sw0 * 8] = *(const bf16x8*)(gkl + ks0 * 8);
            *(bf16x8*)&Ksh[1][kr * 64 + sw1 * 8] = *(const bf16x8*)(gkl + (ks0+1) * 8);
            const int vd  = tid >> 3;                  // 0..63
            const int vs0 = (tid & 7) * 2;             // 0..14
            const bf16* gv = Vt + ((size_t)bh * HDD + vd) * TT + j0;
            const int vw0 = ((vs0     & 8) | ((vs0     ^ vd) & 7));
            const int vw1 = (((vs0+1) & 8) | (((vs0+1) ^ vd) & 7));
            *(bf16x8*)&Vsh[vd * 128 + vw0 * 8] = *(const bf16x8*)(gv + vs0 * 8);
            *(bf16x8*)&Vsh[vd * 128 + vw1 * 8] = *(const bf16x8*)(gv + (vs0+1) * 8);
        }
        __syncthreads();

        // ---- QK^T (+ubias): s[jt][r], row=lg*4+r, col=jt*16+lr
        f32x4 s[8];
#pragma unroll
        for (int jt = 0; jt < 8; ++jt) {
            const int jr = jt * 16 + lr;               // K row in tile
            const int x7 = jr & 7;
            bf16x8 kh0 = *(const bf16x8*)&Ksh[0][jr * 64 + ((lg     ^ x7) * 8)];
            bf16x8 kh1 = *(const bf16x8*)&Ksh[0][jr * 64 + (((4+lg) ^ x7) * 8)];
            bf16x8 kl0 = *(const bf16x8*)&Ksh[1][jr * 64 + ((lg     ^ x7) * 8)];
            bf16x8 kl1 = *(const bf16x8*)&Ksh[1][jr * 64 + (((4+lg) ^ x7) * 8)];
            f32x4 acc = f32x4{0.f,0.f,0.f,0.f};
            acc = mfma16(qh0, kh0, acc); acc = mfma16(qh1, kh1, acc);
            acc = mfma16(qh0, kl0, acc); acc = mfma16(qh1, kl1, acc);
            acc = mfma16(ql0, kh0, acc); acc = mfma16(ql1, kh1, acc);
#pragma unroll
            for (int r = 0; r < 4; ++r)
                acc[r] = acc[r] * 8.0f + (float)ubc[(size_t)(lg * 4 + r) * TT + j0 + jt * 16 + lr];
            s[jt] = acc;
        }

        // ---- tile max -> new running max; rescale factors
        float tm[4];
#pragma unroll
        for (int r = 0; r < 4; ++r) {
            float mm = s[0][r];
#pragma unroll
            for (int jt = 1; jt < 8; ++jt) mm = fmaxf(mm, s[jt][r]);
            tm[r] = mm;
        }
#pragma unroll
        for (int off = 1; off < 16; off <<= 1)
#pragma unroll
            for (int r = 0; r < 4; ++r) tm[r] = fmaxf(tm[r], __shfl_xor(tm[r], off));
        float e[4], mnew[4], mexp[4];
#pragma unroll
        for (int r = 0; r < 4; ++r) {
            mnew[r] = fmaxf(mrun[r], tm[r]);
            e[r]    = (mrun[r] == -INFINITY) ? 0.f : __expf(mrun[r] - mnew[r]);
            mexp[r] = (mnew[r] == -INFINITY) ? 0.f : mnew[r];
            mrun[r] = mnew[r];
        }
#pragma unroll
        for (int dt = 0; dt < 4; ++dt)
#pragma unroll
            for (int r = 0; r < 4; ++r) cacc[dt][r] *= e[r];

        // ---- p = exp(s - mrun); to swizzled Psh + global pA; row sums
        float psum[4] = {0.f, 0.f, 0.f, 0.f};
#pragma unroll
        for (int jt = 0; jt < 8; ++jt) {
#pragma unroll
            for (int r = 0; r < 4; ++r) {
                const float p = __expf(s[jt][r] - mexp[r]);
                psum[r] += p;
                const bf16 pb = (bf16)p;
                const int row = lg * 4 + r;
                const int col = jt * 16 + lr;
                const int sseg = ((col >> 3) & 8) | (((col >> 3) ^ row) & 7);
                Psh[w][row * 128 + sseg * 8 + (col & 7)] = pb;
                pA[(size_t)row * TT + j0 + col] = pb;
            }
        }
#pragma unroll
        for (int off = 1; off < 16; off <<= 1)
#pragma unroll
            for (int r = 0; r < 4; ++r) psum[r] += __shfl_xor(psum[r], off);
#pragma unroll
        for (int r = 0; r < 4; ++r) srun[r] = srun[r] * e[r] + psum[r];
        if (lr == 0)
#pragma unroll
            for (int r = 0; r < 4; ++r)
                mS[((size_t)bh * TT + iw + lg * 4 + r) * 8 + tile] = mnew[r];

        __builtin_amdgcn_sched_barrier(0);   // keep P-writes before PV reads (same-wave DS is in-order)

        // ---- PV from swizzled Psh/Vsh
#pragma unroll
        for (int ks = 0; ks < 4; ++ks) {
            const int seg = ks * 4 + lg;               // P col seg
            const int ps  = (seg & 8) | ((seg ^ lr) & 7);
            bf16x8 a = *(const bf16x8*)&Psh[w][lr * 128 + ps * 8];
#pragma unroll
            for (int dt = 0; dt < 4; ++dt) {
                const int d  = dt * 16 + lr;
                const int vs = (seg & 8) | ((seg ^ d) & 7);
                bf16x8 bv = *(const bf16x8*)&Vsh[d * 128 + vs * 8];
                cacc[dt] = mfma16(a, bv, cacc[dt]);
            }
        }
    }

    // ---- epilogue: ctx = cacc / S; store S
    float inv[4];
#pragma unroll
    for (int r = 0; r < 4; ++r) inv[r] = 1.0f / srun[r];
#pragma unroll
    for (int dt = 0; dt < 4; ++dt)
#pragma unroll
        for (int r = 0; r < 4; ++r) {
            const int i = iw + lg * 4 + r;
            ctx[((size_t)b * TT + i) * EE + h * HDD + dt * 16 + lr] = (bf16)(cacc[dt][r] * inv[r]);
        }
    if (lr == 0)
#pragma unroll
        for (int r = 0; r < 4; ++r)
            mS[MTOFF + (size_t)bh * TT + iw + lg * 4 + r] = srun[r];
}

// ---------------------------------------------------------------- k_norm: p(bf16) -> attn(f32), in place
__global__ __launch_bounds__(256) void k_norm(const float* __restrict__ mS, float* __restrict__ A)
{
    const int bh = blockIdx.x;
    const int i0 = blockIdx.y * 16;
    const int tid = threadIdx.x;

    __shared__ __align__(16) bf16 pbuf[16 * 1024];    // 32 KB
    __shared__ float fac[16][8];

    const bf16* pA = (const bf16*)(A + ((size_t)bh * TT + i0) * TT) + 16 * TT;
#pragma unroll
    for (int k = 0; k < 8; ++k)
        *(bf16x8*)&pbuf[(size_t)tid * 64 + k * 8] = *(const bf16x8*)(pA + (size_t)tid * 64 + k * 8);

    if (tid < 128) {
        const int row = tid >> 3, t = tid & 7;
        const float mt = mS[((size_t)bh * TT + i0 + row) * 8 + t];
        const float m7 = mS[((size_t)bh * TT + i0 + row) * 8 + 7];
        const float S  = mS[MTOFF + (size_t)bh * TT + i0 + row];
        fac[row][t] = __expf(mt - m7) / S;
    }
    __syncthreads();

    float* Ar = A + ((size_t)bh * TT + i0) * TT;
    const int row = tid >> 4;
    const int c0  = (tid & 15) * 64;
#pragma unroll
    for (int k = 0; k < 16; ++k) {
        const int c = c0 + k * 4;
        const float f = fac[row][c >> 7];
        f32x4 o;
#pragma unroll
        for (int e2 = 0; e2 < 4; ++e2) o[e2] = (float)pbuf[row * 1024 + c + e2] * f;
        *(f32x4*)&Ar[(size_t)row * TT + c] = o;
    }
}

// ---------------------------------------------------------------- k_out2 (unchanged)
__global__ __launch_bounds__(256) void k_out2(
    const bf16* __restrict__ ctx, const bf16* __restrict__ woh,
    const float* __restrict__ bo, float* __restrict__ out)
{
    const int rb = blockIdx.x;
    const int cb = blockIdx.y;
    const int wid = threadIdx.x >> 6;
    const int l = threadIdx.x & 63;
    const int lg = l >> 4, lr = l & 15;
    const int row = rb * 64 + wid * 16 + lr;

    f32x4 acc[4];
#pragma unroll
    for (int c = 0; c < 4; ++c) acc[c] = f32x4{0.f,0.f,0.f,0.f};

    for (int ks = 0; ks < 16; ++ks) {
        const int e0 = ks * 32 + lg * 8;
        bf16x8 af = *(const bf16x8*)(ctx + (size_t)row * EE + e0);
#pragma unroll
        for (int c = 0; c < 4; ++c) {
            const int f = cb * 64 + c * 16 + lr;
            bf16x8 wf = *(const bf16x8*)(woh + (size_t)f * EE + e0);
            acc[c] = mfma16(af, wf, acc[c]);
        }
    }
#pragma unroll
    for (int c = 0; c < 4; ++c) {
        const int f = cb * 64 + c * 16 + lr;
        const float bov = bo[f];
#pragma unroll
        for (int r = 0; r < 4; ++r) {
            const int orow = rb * 64 + wid * 16 + lg * 4 + r;
            out[(size_t)orow * EE + f] = acc[c][r] + bov;
        }
    }
}

// ----------------------------------------------------------------
extern "C" void kernel_launch(void* const* d_in, const int* in_sizes, int n_in,
                              void* d_out, int out_size, void* d_ws, size_t ws_size,
                              hipStream_t stream)
{
    (void)in_sizes; (void)n_in; (void)out_size; (void)ws_size;
    const float* x  = (const float*)d_in[0];
    const float* u  = (const float*)d_in[1];
    const unsigned char* umask = (const unsigned char*)d_in[2];
    const float* wq = (const float*)d_in[3];
    const float* wk = (const float*)d_in[4];
    const float* wv = (const float*)d_in[5];
    const float* wo = (const float*)d_in[6];
    const float* bo = (const float*)d_in[7];
    const float* wu = (const float*)d_in[8];
    const float* bu = (const float*)d_in[9];

    float* out = (float*)d_out;
    float* A   = out + (size_t)BSZ * TT * EE;       // attn region of d_out

    const size_t qs  = (size_t)BSZ * HH * TT * HDD; // 4,194,304
    const size_t wsz = (size_t)EE * EE;             // 262,144
    const size_t xs  = (size_t)BSZ * TT * EE;       // 4,194,304
    bf16* Qh  = (bf16*)d_ws;
    bf16* Ql  = Qh + qs;
    bf16* Kh  = Ql + qs;
    bf16* Kl  = Kh + qs;
    bf16* Vt  = Kl + qs;
    bf16* ctx = Vt + qs;
    bf16* wqh = ctx + qs;
    bf16* wql = wqh + wsz;
    bf16* wkh = wql + wsz;
    bf16* wkl = wkh + wsz;
    bf16* wvh = wkl + wsz;
    bf16* woh = wvh + wsz;
    bf16* xh  = woh + wsz;
    bf16* xl  = xh  + xs;
    float* mS = (float*)(xl + xs);                  // m_tile[64][1024][8] + S[64][1024] = 2.25 MB

    k_split_all<<<dim3(2048, 5), 256, 0, stream>>>(wq, wk, wv, wo, x,
                                                   wqh, wql, wkh, wkl, wvh, woh, xh, xl);
    k_ubias2<<<dim3(16, 16, 8), 256, 0, stream>>>(u, umask, wu, bu, A);
    k_proj2 <<<dim3(128, 8), 256, 0, stream>>>(xh, xl, wqh, wql, wkh, wkl, wvh, Qh, Ql, Kh, Kl, Vt);
    k_fused4<<<512, 512, 0, stream>>>(Qh, Ql, Kh, Kl, Vt, A, ctx, mS);
    k_norm  <<<dim3(64, 64), 256, 0, stream>>>(mS, A);
    k_out2  <<<dim3(128, 8), 256, 0, stream>>>(ctx, woh, bo, out);
}

// Round 6
// 579.941 us; speedup vs baseline: 1.4132x; 1.4132x over previous
//
#include <hip/hip_runtime.h>
#include <cmath>

#define BSZ 8
#define TT  1024
#define EE  512
#define HH  8
#define CUc 6
#define HDD 64

typedef __bf16 bf16;
typedef __attribute__((ext_vector_type(4))) float f32x4;
typedef __attribute__((ext_vector_type(8))) float f32x8;
typedef __attribute__((ext_vector_type(8))) bf16  bf16x8;

static __device__ __forceinline__ f32x4 mfma16(bf16x8 a, bf16x8 b, f32x4 c) {
    return __builtin_amdgcn_mfma_f32_16x16x32_bf16(a, b, c, 0, 0, 0);
}

// ---------------------------------------------------------------- k_split_all
__global__ __launch_bounds__(256) void k_split_all(
    const float* __restrict__ wq, const float* __restrict__ wk,
    const float* __restrict__ wv, const float* __restrict__ wo,
    const float* __restrict__ x,
    bf16* __restrict__ wqh, bf16* __restrict__ wql,
    bf16* __restrict__ wkh, bf16* __restrict__ wkl,
    bf16* __restrict__ wvh, bf16* __restrict__ woh,
    bf16* __restrict__ xh,  bf16* __restrict__ xl)
{
    const float* src; bf16* hi; bf16* lo; int n;
    switch (blockIdx.y) {
        case 0: src = wq; hi = wqh; lo = wql;     n = EE * EE;       break;
        case 1: src = wk; hi = wkh; lo = wkl;     n = EE * EE;       break;
        case 2: src = wv; hi = wvh; lo = nullptr; n = EE * EE;       break;
        case 3: src = wo; hi = woh; lo = nullptr; n = EE * EE;       break;
        default: src = x; hi = xh;  lo = xl;      n = BSZ * TT * EE; break;
    }
    const int i = (blockIdx.x * 256 + threadIdx.x) * 8;
    if (i >= n) return;
    f32x8 v = *(const f32x8*)(src + i);
    bf16x8 h8, l8;
#pragma unroll
    for (int k = 0; k < 8; ++k) {
        bf16 h = (bf16)v[k];
        h8[k] = h;
        l8[k] = (bf16)(v[k] - (float)h);
    }
    *(bf16x8*)(hi + i) = h8;
    if (lo) *(bf16x8*)(lo + i) = l8;
}

// ---------------------------------------------------------------- k_proj2
__global__ __launch_bounds__(256) void k_proj2(
    const bf16* __restrict__ xh, const bf16* __restrict__ xl,
    const bf16* __restrict__ wqh, const bf16* __restrict__ wql,
    const bf16* __restrict__ wkh, const bf16* __restrict__ wkl,
    const bf16* __restrict__ wvh,
    bf16* __restrict__ Qh, bf16* __restrict__ Ql,
    bf16* __restrict__ Kh, bf16* __restrict__ Kl,
    bf16* __restrict__ Vt)
{
    const int rb = blockIdx.x;
    const int cb = blockIdx.y;
    const int wid = threadIdx.x >> 6;
    const int l   = threadIdx.x & 63;
    const int lg = l >> 4, lr = l & 15;
    const int row = rb * 64 + wid * 16 + lr;

    f32x4 aq[4], ak[4], av[4];
#pragma unroll
    for (int c = 0; c < 4; ++c) {
        aq[c] = f32x4{0.f,0.f,0.f,0.f}; ak[c] = f32x4{0.f,0.f,0.f,0.f}; av[c] = f32x4{0.f,0.f,0.f,0.f};
    }

    for (int ks = 0; ks < 16; ++ks) {
        const int e0 = ks * 32 + lg * 8;
        bf16x8 xhv = *(const bf16x8*)(xh + (size_t)row * EE + e0);
        bf16x8 xlv = *(const bf16x8*)(xl + (size_t)row * EE + e0);
#pragma unroll
        for (int c = 0; c < 4; ++c) {
            const int f = cb * 64 + c * 16 + lr;
            const size_t wo = (size_t)f * EE + e0;
            bf16x8 qh = *(const bf16x8*)(wqh + wo);
            bf16x8 ql = *(const bf16x8*)(wql + wo);
            bf16x8 kh = *(const bf16x8*)(wkh + wo);
            bf16x8 kl = *(const bf16x8*)(wkl + wo);
            bf16x8 vh = *(const bf16x8*)(wvh + wo);
            aq[c] = mfma16(xhv, qh, aq[c]); aq[c] = mfma16(xhv, ql, aq[c]); aq[c] = mfma16(xlv, qh, aq[c]);
            ak[c] = mfma16(xhv, kh, ak[c]); ak[c] = mfma16(xhv, kl, ak[c]); ak[c] = mfma16(xlv, kh, ak[c]);
            av[c] = mfma16(xhv, vh, av[c]);
        }
    }

#pragma unroll
    for (int c = 0; c < 4; ++c)
#pragma unroll
        for (int r = 0; r < 4; ++r) {
            const int orow = rb * 64 + wid * 16 + lg * 4 + r;
            const int b = orow >> 10, t = orow & 1023;
            const int f = cb * 64 + c * 16 + lr;
            const int h = f >> 6, d = f & 63;
            const size_t idx = ((size_t)(b * HH + h) * TT + t) * HDD + d;
            float vq = aq[c][r];
            bf16 qhi = (bf16)vq; Qh[idx] = qhi; Ql[idx] = (bf16)(vq - (float)qhi);
            float vk = ak[c][r];
            bf16 khi = (bf16)vk; Kh[idx] = khi; Kl[idx] = (bf16)(vk - (float)khi);
            Vt[(((size_t)(b * HH + h) * HDD + d) * TT) + t] = (bf16)av[c][r];
        }
}

// ---------------------------------------------------------------- k_ubias2 (coalesced writes)
// UB chunk (b,h,i16) = (bf16*)(A + ((bh*1024 + i16*16) * 1024)); layout [i&15][j]
__global__ __launch_bounds__(256) void k_ubias2(
    const float* __restrict__ u, const unsigned char* __restrict__ umask,
    const float* __restrict__ wu, const float* __restrict__ bu,
    float* __restrict__ A)
{
    __shared__ __align__(16) unsigned char msk[64][64];   // [j-rel][i-rel]
    const int b  = blockIdx.z;
    const int i0 = blockIdx.y * 64;
    const int j0 = blockIdx.x * 64;
    const int t  = threadIdx.x;

    {
        const int jj  = t >> 2;
        const int seg = (t & 3) * 16;
        *(uint4*)(&msk[jj][seg]) =
            *(const uint4*)(umask + ((size_t)b * TT + (j0 + jj)) * TT + i0 + seg);
    }
    float wuv[HH][CUc], buv[HH];
#pragma unroll
    for (int h = 0; h < HH; ++h) {
        buv[h] = bu[h];
#pragma unroll
        for (int c = 0; c < CUc; ++c) wuv[h][c] = wu[h * CUc + c];
    }
    __syncthreads();

    const int j = j0 + (t & 63);
    for (int ii = (t >> 6); ii < 64; ii += 4) {
        const int i = i0 + ii;
        float uv[CUc];
#pragma unroll
        for (int c = 0; c < CUc; ++c)
            uv[c] = u[(((size_t)b * CUc + c) * TT + i) * TT + j];
        const bool mk = msk[t & 63][ii] != 0;
#pragma unroll
        for (int h = 0; h < HH; ++h) {
            float v = buv[h];
#pragma unroll
            for (int c = 0; c < CUc; ++c) v += uv[c] * wuv[h][c];
            if (mk) v = -INFINITY;
            bf16* ub = (bf16*)(A + ((size_t)(b * HH + h) * TT + (i & ~15)) * TT);
            ub[(i & 15) * TT + j] = (bf16)v;
        }
    }
}

// ---------------------------------------------------------------- k_fused5: (bh,i16) block, 1 barrier,
// software-pipelined K/V register stages, deferred-rescale softmax, P re-read for attn write.
#define LOADK1(ARR, JT) {                                                       \
    const size_t ko = (size_t)(jw + (JT) * 16 + lr) * HDD + lg * 8;             \
    ARR[0] = *(const bf16x8*)(kph + ko);                                        \
    ARR[1] = *(const bf16x8*)(kph + ko + 32);                                   \
    ARR[2] = *(const bf16x8*)(kpl + ko);                                        \
    ARR[3] = *(const bf16x8*)(kpl + ko + 32);                                   \
  }
#define COMPK1(ARR, JT) {                                                       \
    f32x4 acc = f32x4{0.f,0.f,0.f,0.f};                                         \
    acc = mfma16(qh0, ARR[0], acc); acc = mfma16(qh1, ARR[1], acc);             \
    acc = mfma16(qh0, ARR[2], acc); acc = mfma16(qh1, ARR[3], acc);             \
    acc = mfma16(ql0, ARR[0], acc); acc = mfma16(ql1, ARR[1], acc);             \
    _Pragma("unroll")                                                           \
    for (int r = 0; r < 4; ++r) acc[r] = acc[r] * 8.0f + (float)ubv[JT][r];     \
    s[JT] = acc;                                                                \
  }
#define LOADV1(ARR, KS) {                                                       \
    const size_t vo = (size_t)lr * TT + jw + (KS) * 32 + lg * 8;                \
    ARR[0] = *(const bf16x8*)(vp + vo);                                         \
    ARR[1] = *(const bf16x8*)(vp + vo + (size_t)16 * TT);                       \
    ARR[2] = *(const bf16x8*)(vp + vo + (size_t)32 * TT);                       \
    ARR[3] = *(const bf16x8*)(vp + vo + (size_t)48 * TT);                       \
  }
#define COMPV1(ARR, KS) {                                                       \
    bf16x8 a = *(const bf16x8*)&P[lr][jw + (KS) * 32 + lg * 8];                 \
    cacc[0] = mfma16(a, ARR[0], cacc[0]); cacc[1] = mfma16(a, ARR[1], cacc[1]); \
    cacc[2] = mfma16(a, ARR[2], cacc[2]); cacc[3] = mfma16(a, ARR[3], cacc[3]); \
  }

__global__ __launch_bounds__(512, 4) void k_fused5(
    const bf16* __restrict__ Qh, const bf16* __restrict__ Ql,
    const bf16* __restrict__ Kh, const bf16* __restrict__ Kl,
    const bf16* __restrict__ Vt,
    float* __restrict__ A, bf16* __restrict__ ctx)
{
    const int g  = blockIdx.x;
    const int bh = ((g >> 9) << 3) | (g & 7);   // XCD g%8 works one bh at a time
    const int ib = (g >> 3) & 63;
    const int b  = bh >> 3, h = bh & 7;
    const int i0 = ib * 16;
    const int w  = threadIdx.x >> 6;            // 8 waves; wave owns j in [w*128, w*128+128)
    const int l  = threadIdx.x & 63;
    const int lg = l >> 4, lr = l & 15;
    const int jw = w * 128;

    __shared__ __align__(16) bf16 P[16][1030];          // odd dword stride: conflict-free b128
    __shared__ __align__(16) bf16 ctxred[8][16][64];    // 16 KB
    __shared__ float mred[8][16], sred[8][16];

    // ---- UB prefetch (32 scalar loads, mostly L3 hits; independent, all in flight)
    const bf16* ubc = (const bf16*)(A + ((size_t)bh * TT + i0) * TT);
    bf16 ubv[8][4];
#pragma unroll
    for (int jt = 0; jt < 8; ++jt)
#pragma unroll
        for (int r = 0; r < 4; ++r)
            ubv[jt][r] = ubc[(size_t)(lg * 4 + r) * TT + jw + jt * 16 + lr];

    // ---- Q fragments
    const bf16* qph = Qh + ((size_t)bh * TT + i0) * HDD;
    const bf16* qpl = Ql + ((size_t)bh * TT + i0) * HDD;
    bf16x8 qh0 = *(const bf16x8*)(qph + lr * HDD + lg * 8);
    bf16x8 qh1 = *(const bf16x8*)(qph + lr * HDD + 32 + lg * 8);
    bf16x8 ql0 = *(const bf16x8*)(qpl + lr * HDD + lg * 8);
    bf16x8 ql1 = *(const bf16x8*)(qpl + lr * HDD + 32 + lg * 8);

    const bf16* kph = Kh + (size_t)bh * TT * HDD;
    const bf16* kpl = Kl + (size_t)bh * TT * HDD;
    const bf16* vp  = Vt + (size_t)bh * HDD * TT;

    // ---- QK^T: 2-stage register pipeline over 8 jt tiles
    f32x4 s[8];
    bf16x8 kA[4], kB[4];
    LOADK1(kA, 0); LOADK1(kB, 1);
    COMPK1(kA, 0); LOADK1(kA, 2);
    COMPK1(kB, 1); LOADK1(kB, 3);
    COMPK1(kA, 2); LOADK1(kA, 4);
    COMPK1(kB, 3); LOADK1(kB, 5);
    COMPK1(kA, 4); LOADK1(kA, 6);
    COMPK1(kB, 5); LOADK1(kB, 7);
    COMPK1(kA, 6);
    COMPK1(kB, 7);

    // ---- issue first V stages now: they fly under the softmax VALU work
    bf16x8 vA[4], vB[4];
    LOADV1(vA, 0); LOADV1(vB, 1);

    // ---- wave-local row max over own 128 cols
    float m[4];
#pragma unroll
    for (int r = 0; r < 4; ++r) {
        float mm = s[0][r];
#pragma unroll
        for (int jt = 1; jt < 8; ++jt) mm = fmaxf(mm, s[jt][r]);
        m[r] = mm;
    }
#pragma unroll
    for (int off = 1; off < 16; off <<= 1)
#pragma unroll
        for (int r = 0; r < 4; ++r) m[r] = fmaxf(m[r], __shfl_xor(m[r], off));

    // ---- exp vs local max; P -> LDS; local row sums (s regs die here)
    float mexp[4];
#pragma unroll
    for (int r = 0; r < 4; ++r) mexp[r] = (m[r] == -INFINITY) ? 0.f : m[r];
    float sum[4] = {0.f, 0.f, 0.f, 0.f};
#pragma unroll
    for (int jt = 0; jt < 8; ++jt)
#pragma unroll
        for (int r = 0; r < 4; ++r) {
            float p = __expf(s[jt][r] - mexp[r]);
            sum[r] += p;
            P[lg * 4 + r][jw + jt * 16 + lr] = (bf16)p;
        }
#pragma unroll
    for (int off = 1; off < 16; off <<= 1)
#pragma unroll
        for (int r = 0; r < 4; ++r) sum[r] += __shfl_xor(sum[r], off);
    if (lr == 0)
#pragma unroll
        for (int r = 0; r < 4; ++r) { mred[w][lg * 4 + r] = m[r]; sred[w][lg * 4 + r] = sum[r]; }

    // ---- PV on own k-slice, 2-stage V pipeline
    f32x4 cacc[4];
#pragma unroll
    for (int dt = 0; dt < 4; ++dt) cacc[dt] = f32x4{0.f,0.f,0.f,0.f};
    COMPV1(vA, 0); LOADV1(vA, 2);
    COMPV1(vB, 1); LOADV1(vB, 3);
    COMPV1(vA, 2);
    COMPV1(vB, 3);
#pragma unroll
    for (int dt = 0; dt < 4; ++dt)
#pragma unroll
        for (int r = 0; r < 4; ++r)
            ctxred[w][lg * 4 + r][dt * 16 + lr] = (bf16)cacc[dt][r];

    __syncthreads();                                     // the ONE barrier

    // ---- global (M,S); attn = P * exp(m_w - M)/S (P re-read from LDS)
    float fac[4];
#pragma unroll
    for (int r = 0; r < 4; ++r) {
        const int row = lg * 4 + r;
        float M = mred[0][row];
#pragma unroll
        for (int wv = 1; wv < 8; ++wv) M = fmaxf(M, mred[wv][row]);
        float S = 0.f;
#pragma unroll
        for (int wv = 0; wv < 8; ++wv) S += sred[wv][row] * __expf(mred[wv][row] - M);
        fac[r] = __expf(m[r] - M) / S;
    }
    float* Ar = A + ((size_t)bh * TT + i0) * TT;
#pragma unroll
    for (int jt = 0; jt < 8; ++jt)
#pragma unroll
        for (int r = 0; r < 4; ++r)
            Ar[(size_t)(lg * 4 + r) * TT + jw + jt * 16 + lr] =
                (float)P[lg * 4 + r][jw + jt * 16 + lr] * fac[r];

    // ---- ctx combine
    for (int o = threadIdx.x; o < 16 * 64; o += 512) {
        const int row = o >> 6, d = o & 63;
        float M = mred[0][row];
#pragma unroll
        for (int wv = 1; wv < 8; ++wv) M = fmaxf(M, mred[wv][row]);
        float S = 0.f, sm = 0.f;
#pragma unroll
        for (int wv = 0; wv < 8; ++wv) {
            const float e = __expf(mred[wv][row] - M);
            S  += sred[wv][row] * e;
            sm += (float)ctxred[wv][row][d] * e;
        }
        ctx[((size_t)b * TT + i0 + row) * EE + h * HDD + d] = (bf16)(sm / S);
    }
}

// ---------------------------------------------------------------- k_out2
__global__ __launch_bounds__(256) void k_out2(
    const bf16* __restrict__ ctx, const bf16* __restrict__ woh,
    const float* __restrict__ bo, float* __restrict__ out)
{
    const int rb = blockIdx.x;
    const int cb = blockIdx.y;
    const int wid = threadIdx.x >> 6;
    const int l = threadIdx.x & 63;
    const int lg = l >> 4, lr = l & 15;
    const int row = rb * 64 + wid * 16 + lr;

    f32x4 acc[4];
#pragma unroll
    for (int c = 0; c < 4; ++c) acc[c] = f32x4{0.f,0.f,0.f,0.f};

    for (int ks = 0; ks < 16; ++ks) {
        const int e0 = ks * 32 + lg * 8;
        bf16x8 af = *(const bf16x8*)(ctx + (size_t)row * EE + e0);
#pragma unroll
        for (int c = 0; c < 4; ++c) {
            const int f = cb * 64 + c * 16 + lr;
            bf16x8 wf = *(const bf16x8*)(woh + (size_t)f * EE + e0);
            acc[c] = mfma16(af, wf, acc[c]);
        }
    }
#pragma unroll
    for (int c = 0; c < 4; ++c) {
        const int f = cb * 64 + c * 16 + lr;
        const float bov = bo[f];
#pragma unroll
        for (int r = 0; r < 4; ++r) {
            const int orow = rb * 64 + wid * 16 + lg * 4 + r;
            out[(size_t)orow * EE + f] = acc[c][r] + bov;
        }
    }
}

// ----------------------------------------------------------------
extern "C" void kernel_launch(void* const* d_in, const int* in_sizes, int n_in,
                              void* d_out, int out_size, void* d_ws, size_t ws_size,
                              hipStream_t stream)
{
    (void)in_sizes; (void)n_in; (void)out_size; (void)ws_size;
    const float* x  = (const float*)d_in[0];
    const float* u  = (const float*)d_in[1];
    const unsigned char* umask = (const unsigned char*)d_in[2];
    const float* wq = (const float*)d_in[3];
    const float* wk = (const float*)d_in[4];
    const float* wv = (const float*)d_in[5];
    const float* wo = (const float*)d_in[6];
    const float* bo = (const float*)d_in[7];
    const float* wu = (const float*)d_in[8];
    const float* bu = (const float*)d_in[9];

    float* out = (float*)d_out;
    float* A   = out + (size_t)BSZ * TT * EE;       // attn region of d_out

    const size_t qs  = (size_t)BSZ * HH * TT * HDD; // 4,194,304
    const size_t wsz = (size_t)EE * EE;             // 262,144
    const size_t xs  = (size_t)BSZ * TT * EE;       // 4,194,304
    bf16* Qh  = (bf16*)d_ws;
    bf16* Ql  = Qh + qs;
    bf16* Kh  = Ql + qs;
    bf16* Kl  = Kh + qs;
    bf16* Vt  = Kl + qs;
    bf16* ctx = Vt + qs;
    bf16* wqh = ctx + qs;
    bf16* wql = wqh + wsz;
    bf16* wkh = wql + wsz;
    bf16* wkl = wkh + wsz;
    bf16* wvh = wkl + wsz;
    bf16* woh = wvh + wsz;
    bf16* xh  = woh + wsz;
    bf16* xl  = xh  + xs;

    k_split_all<<<dim3(2048, 5), 256, 0, stream>>>(wq, wk, wv, wo, x,
                                                   wqh, wql, wkh, wkl, wvh, woh, xh, xl);
    k_ubias2<<<dim3(16, 16, 8), 256, 0, stream>>>(u, umask, wu, bu, A);
    k_proj2 <<<dim3(128, 8), 256, 0, stream>>>(xh, xl, wqh, wql, wkh, wkl, wvh, Qh, Ql, Kh, Kl, Vt);
    k_fused5<<<4096, 512, 0, stream>>>(Qh, Ql, Kh, Kl, Vt, A, ctx);
    k_out2  <<<dim3(128, 8), 256, 0, stream>>>(ctx, woh, bo, out);
}